// Round 6
// baseline (821.824 us; speedup 1.0000x reference)
//
#include <hip/hip_runtime.h>

#define B_ 4
#define S_ 2048
#define HID_ 2048
#define NH_ 16
#define NKV_ 4
#define HD_ 128
#define NTOK (B_ * S_)                 // 8192
#define QKV_N 3072                     // (NH + 2*NKV) * HD
#define KO_N 512                       // K-only row length (4 kv heads * 128)
#define SCALE_ 0.08838834764831845f    // 128^-0.5
#define QSC_ 0.12751743f               // SCALE_ * log2(e)  (base-2 softmax)
#define LOG2_10K 13.287712379549449f   // log2(10000)
#define NEG_ -30000.0f

typedef __attribute__((ext_vector_type(8))) short short8;
typedef __attribute__((ext_vector_type(4))) short short4v;
typedef __attribute__((ext_vector_type(4))) float f32x4;
typedef unsigned short ushort_t;
typedef unsigned int uint32;

__device__ __forceinline__ float sanit(float x) {
    if (!(x == x)) x = 0.0f;
    return fminf(fmaxf(x, -65504.0f), 65504.0f);
}
__device__ __forceinline__ ushort_t f2bf(float f) {
    union { float f; uint32 u; } c; c.f = f;
    uint32 u = c.u;
    u += 0x7fffu + ((u >> 16) & 1u);          // round-to-nearest-even
    return (ushort_t)(u >> 16);
}
__device__ __forceinline__ ushort_t f2bf_s(float f) { return f2bf(sanit(f)); }
__device__ __forceinline__ float bf2f(ushort_t h) {
    union { float f; uint32 u; } c; c.u = ((uint32)h) << 16;
    return c.f;
}

// async global->LDS, 16B per lane, linear dest (wave-uniform base + lane*16)
__device__ __forceinline__ void gl16(const ushort_t* g, ushort_t* l) {
    __builtin_amdgcn_global_load_lds(
        (__attribute__((address_space(1))) void*)g,
        (__attribute__((address_space(3))) void*)l, 16, 0, 0);
}

// ---------------------------------------------------------------------------
// Prepass 1: X fp32 [8192][2048] -> bf16 (vectorized, 8 elems/thread)
// ---------------------------------------------------------------------------
__global__ void convx_kernel(const float* __restrict__ X, ushort_t* __restrict__ Xb) {
    size_t i = (size_t)blockIdx.x * blockDim.x + threadIdx.x;
    const float4 a = *(const float4*)(X + i * 8);
    const float4 b = *(const float4*)(X + i * 8 + 4);
    short8 p;
    p[0] = (short)f2bf(a.x); p[1] = (short)f2bf(a.y);
    p[2] = (short)f2bf(a.z); p[3] = (short)f2bf(a.w);
    p[4] = (short)f2bf(b.x); p[5] = (short)f2bf(b.y);
    p[6] = (short)f2bf(b.z); p[7] = (short)f2bf(b.w);
    *(short8*)(Xb + i * 8) = p;
}

// ---------------------------------------------------------------------------
// Prepass 2: W fp32 [K][N] -> Wt bf16 [N][K] (32x32 LDS tile transpose)
// ---------------------------------------------------------------------------
__global__ void wtrans_kernel(const float* __restrict__ W, ushort_t* __restrict__ Wt,
                              int K, int N) {
    __shared__ float tile[32][33];
    const int n0 = blockIdx.x * 32;
    const int k0 = blockIdx.y * 32;
    const int t  = threadIdx.x;        // 256
    const int r  = t >> 3;             // 0..31
    const int c  = (t & 7) * 4;        // 0..28
    const float4 v = *(const float4*)(W + (size_t)(k0 + r) * N + n0 + c);
    tile[r][c] = v.x; tile[r][c + 1] = v.y; tile[r][c + 2] = v.z; tile[r][c + 3] = v.w;
    __syncthreads();
    short4v p;
    p[0] = (short)f2bf(tile[c][r]);
    p[1] = (short)f2bf(tile[c + 1][r]);
    p[2] = (short)f2bf(tile[c + 2][r]);
    p[3] = (short)f2bf(tile[c + 3][r]);
    *(short4v*)(Wt + (size_t)(n0 + r) * K + k0 + c) = p;
}

// ---------------------------------------------------------------------------
// Prepass 3: RoPE cos/sin tables [S][64] fp32
// ---------------------------------------------------------------------------
__global__ void ropetab_kernel(float* __restrict__ ct, float* __restrict__ st) {
    int p = blockIdx.x * blockDim.x + threadIdx.x;   // 0 .. S_*64-1
    int s = p >> 6, d = p & 63;
    float inv = exp2f(-(float)d * (LOG2_10K / 64.0f));
    float ang = (float)s * inv;
    float sn, cs;
    sincosf(ang, &sn, &cs);
    ct[p] = cs; st[p] = sn;
}

// ---------------------------------------------------------------------------
// GEMM: C = A[M,K] @ B, with B given transposed as Bt[N,K]. All bf16 in,
// fp32 acc. m97 structure: 128x128 tile, 4 waves of 64x64, BK=32,
// global_load_lds staging (no LDS writes, no staging VALU).
// SPLIT=1 (QKV): cols <2048 -> Q bf16 (C0); 2048..2559 -> K bf16 (C1);
//                2560..3071 -> V TRANSPOSED bf16 (C2)[vcol*8192 + token].
// SPLIT=0: fp32 epilogue into C0 (ld N).
// ---------------------------------------------------------------------------
template <int SPLIT>
__global__ __launch_bounds__(256, 2) void gemm_bt(
    const ushort_t* __restrict__ A, const ushort_t* __restrict__ Bt,
    void* __restrict__ C0, ushort_t* __restrict__ C1, ushort_t* __restrict__ C2,
    int M, int N, int K) {
    __shared__ __align__(16) ushort_t As[128 * 32];
    __shared__ __align__(16) ushort_t Bs[128 * 32];

    const int tid  = threadIdx.x;
    const int lane = tid & 63;
    const int w    = tid >> 6;
    const int wm   = (w >> 1) * 64;
    const int wn   = (w & 1) * 64;
    const int m0   = blockIdx.y * 128;
    const int n0   = blockIdx.x * 128;
    const int col  = lane & 15;
    const int quad = lane >> 4;

    f32x4 acc[4][4] = {};

    const int sr = tid >> 2;          // 0..63
    const int sk = (tid & 3) * 8;     // {0,8,16,24}
    const ushort_t* ag0 = A + (size_t)(m0 + sr) * K + sk;
    const ushort_t* ag1 = A + (size_t)(m0 + 64 + sr) * K + sk;
    const ushort_t* bg0 = Bt + (size_t)(n0 + sr) * K + sk;
    const ushort_t* bg1 = Bt + (size_t)(n0 + 64 + sr) * K + sk;
    ushort_t* la0 = &As[tid * 8];
    ushort_t* la1 = &As[2048 + tid * 8];
    ushort_t* lb0 = &Bs[tid * 8];
    ushort_t* lb1 = &Bs[2048 + tid * 8];

    for (int k0 = 0; k0 < K; k0 += 32) {
        __syncthreads();
        gl16(ag0 + k0, la0);
        gl16(ag1 + k0, la1);
        gl16(bg0 + k0, lb0);
        gl16(bg1 + k0, lb1);
        __syncthreads();   // compiler drains vmcnt(0) before s_barrier

        short8 af[4], bfr[4];
#pragma unroll
        for (int mt = 0; mt < 4; ++mt)
            af[mt] = *(const short8*)&As[(wm + mt * 16 + col) * 32 + quad * 8];
#pragma unroll
        for (int nt = 0; nt < 4; ++nt)
            bfr[nt] = *(const short8*)&Bs[(wn + nt * 16 + col) * 32 + quad * 8];
#pragma unroll
        for (int mt = 0; mt < 4; ++mt)
#pragma unroll
            for (int nt = 0; nt < 4; ++nt)
                acc[mt][nt] = __builtin_amdgcn_mfma_f32_16x16x32_bf16(
                    af[mt], bfr[nt], acc[mt][nt], 0, 0, 0);
    }

    if (SPLIT) {
        if (n0 >= 2560) {
            // V -> transposed global: 4 consecutive tokens packed per store
#pragma unroll
            for (int mt = 0; mt < 4; ++mt)
#pragma unroll
                for (int nt = 0; nt < 4; ++nt) {
                    int cc   = n0 + wn + nt * 16 + col - 2560;  // 0..511
                    int row0 = m0 + wm + mt * 16 + quad * 4;
                    short4v p;
#pragma unroll
                    for (int r = 0; r < 4; ++r) p[r] = (short)f2bf_s(acc[mt][nt][r]);
                    *(short4v*)&C2[(size_t)cc * NTOK + row0] = p;
                }
        } else {
            ushort_t* dst;
            int ldc, coff;
            if (n0 >= 2048) { dst = C1; ldc = KO_N; coff = 2048; }
            else            { dst = (ushort_t*)C0; ldc = HID_; coff = 0; }
#pragma unroll
            for (int mt = 0; mt < 4; ++mt)
#pragma unroll
                for (int nt = 0; nt < 4; ++nt)
#pragma unroll
                    for (int r = 0; r < 4; ++r) {
                        int row = m0 + wm + mt * 16 + quad * 4 + r;
                        int cc  = n0 + wn + nt * 16 + col - coff;
                        dst[(size_t)row * ldc + cc] = f2bf_s(acc[mt][nt][r]);
                    }
        }
    } else {
        float* dst = (float*)C0;
#pragma unroll
        for (int mt = 0; mt < 4; ++mt)
#pragma unroll
            for (int nt = 0; nt < 4; ++nt)
#pragma unroll
                for (int r = 0; r < 4; ++r) {
                    int row = m0 + wm + mt * 16 + quad * 4 + r;
                    int cc  = n0 + wn + nt * 16 + col;
                    dst[(size_t)row * N + cc] = sanit(acc[mt][nt][r]);
                }
    }
}

// ---------------------------------------------------------------------------
// RoPE in-place, table-driven, vectorized (short8). Q pre-scaled by QSC_
// (base-2 softmax domain). One thread per (tok, head, d-octet).
// ---------------------------------------------------------------------------
__global__ void rope_kernel(ushort_t* __restrict__ qbuf, ushort_t* __restrict__ kb,
                            const float* __restrict__ ct, const float* __restrict__ st) {
    int p = blockIdx.x * blockDim.x + threadIdx.x;   // NTOK*20*8
    int d0   = (p & 7) * 8;
    int rest = p >> 3;
    int head = rest % 20;            // 0..15 Q, 16..19 K
    int tok  = rest / 20;
    int s    = tok & (S_ - 1);

    ushort_t* base;
    float sc;
    if (head < 16) { base = qbuf + (size_t)tok * HID_ + head * HD_ + d0; sc = QSC_; }
    else           { base = kb   + (size_t)tok * KO_N + (head - 16) * HD_ + d0; sc = 1.0f; }

    short8 x1v = *(const short8*)base;
    short8 x2v = *(const short8*)(base + 64);
    const float* cp = ct + s * 64 + d0;
    const float* sp = st + s * 64 + d0;
    short8 r1, r2;
#pragma unroll
    for (int e = 0; e < 8; ++e) {
        float x1 = bf2f((ushort_t)x1v[e]);
        float x2 = bf2f((ushort_t)x2v[e]);
        float cs = cp[e], sn = sp[e];
        r1[e] = (short)f2bf_s((x1 * cs - x2 * sn) * sc);
        r2[e] = (short)f2bf_s((x2 * cs + x1 * sn) * sc);
    }
    *(short8*)base        = r1;
    *(short8*)(base + 64) = r2;
}

// ---------------------------------------------------------------------------
// Flash attention, causal, GQA. 4 waves x 32 Q rows (two 16-row halves),
// BQ=128, BK=64. Each K/V LDS fragment read feeds TWO MFMAs (one per half)
// -> per-block LDS read traffic halved vs 16-rows/wave. Q pre-scaled
// (base-2); MFMA row-sum; defer-max; register prefetch of next K/V tile.
// ---------------------------------------------------------------------------
__global__ __launch_bounds__(256, 2) void flash_kernel(
    const ushort_t* __restrict__ qbuf, const ushort_t* __restrict__ kb,
    const ushort_t* __restrict__ vtg, ushort_t* __restrict__ obuf) {
    __shared__ __align__(16) ushort_t Ks[64][136];   // [j][d], +8 pad
    __shared__ __align__(16) ushort_t Vt[128][72];   // [d][j], +8 pad
    __shared__ __align__(16) ushort_t Ps[4][32][72]; // per-wave 32 P rows

    const int tid  = threadIdx.x;
    const int lane = tid & 63;
    const int w    = tid >> 6;                       // 0..3
    const int col  = lane & 15;
    const int quad = lane >> 4;
    const int q0   = (S_ / 128 - 1 - blockIdx.x) * 128;  // heavy blocks first
    const int h    = blockIdx.y;
    const int b    = blockIdx.z;
    const int kvh  = h >> 2;
    const int bS   = b * S_;

    const int wr   = q0 + w * 32;           // wave's first Q row (32 rows)
    const int wmax = wr + 31;

    short8 qf[2][4];
#pragma unroll
    for (int mh = 0; mh < 2; ++mh) {
        const ushort_t* qp = qbuf + (size_t)(bS + wr + mh * 16 + col) * HID_
                             + h * HD_ + quad * 8;
#pragma unroll
        for (int kt = 0; kt < 4; ++kt) qf[mh][kt] = *(const short8*)(qp + kt * 32);
    }

    short8 vone;
#pragma unroll
    for (int e = 0; e < 8; ++e) vone[e] = (short)0x3F80;   // bf16 1.0

    float m_i[2][4];
#pragma unroll
    for (int mh = 0; mh < 2; ++mh)
#pragma unroll
        for (int r = 0; r < 4; ++r) m_i[mh][r] = NEG_;
    f32x4 o0[8] = {}, o1[8] = {};
    f32x4 lsum0 = {}, lsum1 = {};

    const int ntiles = q0 / 64 + 2;

    // staging maps (256 threads): K 64x128 (4 thr/row), V 128x64 (2 thr/row)
    const int jr = tid >> 2;            // 0..63
    const int kd = (tid & 3) * 32;      // {0,32,64,96}
    const int vd = tid >> 1;            // 0..127
    const int vj = (tid & 1) * 32;      // {0,32}

    const ushort_t* kgb = kb + (size_t)(bS + jr) * KO_N + kvh * HD_ + kd;
    const ushort_t* vgb = vtg + (size_t)(kvh * HD_ + vd) * NTOK + bS + vj;

    float4 pk[4], pv[4];
    // prologue: stage tile 0
#pragma unroll
    for (int i = 0; i < 4; ++i) {
        pk[i] = *(const float4*)(kgb + i * 8);
        pv[i] = *(const float4*)(vgb + i * 8);
    }
#pragma unroll
    for (int i = 0; i < 4; ++i) {
        *(float4*)&Ks[jr][kd + i * 8] = pk[i];
        *(float4*)&Vt[vd][vj + i * 8] = pv[i];
    }
    __syncthreads();

    for (int t = 0; t < ntiles; ++t) {
        const int j0 = t * 64;
        const bool pre = (t + 1 < ntiles);
        if (pre) {  // issue next tile's loads now; latency hides under compute
            const ushort_t* kgn = kgb + (size_t)(j0 + 64) * KO_N;
            const ushort_t* vgn = vgb + (j0 + 64);
#pragma unroll
            for (int i = 0; i < 4; ++i) {
                pk[i] = *(const float4*)(kgn + i * 8);
                pv[i] = *(const float4*)(vgn + i * 8);
            }
        }

        if (j0 <= wmax) {   // wave-uniform: skip fully-masked tiles
            // S = Q K^T : each kf read feeds BOTH halves
            f32x4 s0[4] = {}, s1[4] = {};
#pragma unroll
            for (int ct = 0; ct < 4; ++ct)
#pragma unroll
                for (int kt = 0; kt < 4; ++kt) {
                    short8 kf = *(const short8*)&Ks[ct * 16 + col][kt * 32 + quad * 8];
                    s0[ct] = __builtin_amdgcn_mfma_f32_16x16x32_bf16(qf[0][kt], kf, s0[ct], 0, 0, 0);
                    s1[ct] = __builtin_amdgcn_mfma_f32_16x16x32_bf16(qf[1][kt], kf, s1[ct], 0, 0, 0);
                }

            // causal mask only on diagonal-adjacent tiles
            if (j0 + 64 > wr) {
#pragma unroll
                for (int ct = 0; ct < 4; ++ct) {
                    int jg = j0 + ct * 16 + col;
#pragma unroll
                    for (int r = 0; r < 4; ++r) {
                        if (jg > wr + quad * 4 + r)      s0[ct][r] = NEG_;
                        if (jg > wr + 16 + quad * 4 + r) s1[ct][r] = NEG_;
                    }
                }
            }

            // row max (each row lives in one quad's 16 lanes)
            float mx0[4], mx1[4];
#pragma unroll
            for (int r = 0; r < 4; ++r) {
                float a = fmaxf(fmaxf(s0[0][r], s0[1][r]), fmaxf(s0[2][r], s0[3][r]));
                float c = fmaxf(fmaxf(s1[0][r], s1[1][r]), fmaxf(s1[2][r], s1[3][r]));
#pragma unroll
                for (int off = 1; off < 16; off <<= 1) {
                    a = fmaxf(a, __shfl_xor(a, off, 64));
                    c = fmaxf(c, __shfl_xor(c, off, 64));
                }
                mx0[r] = a; mx1[r] = c;
            }
            // defer-max: skip rescale when max growth <= 8 (base-2: P <= 256)
            int ok = 1;
#pragma unroll
            for (int r = 0; r < 4; ++r) {
                ok &= (mx0[r] <= m_i[0][r] + 8.0f) ? 1 : 0;
                ok &= (mx1[r] <= m_i[1][r] + 8.0f) ? 1 : 0;
            }
            if (!__all(ok)) {
#pragma unroll
                for (int r = 0; r < 4; ++r) {
                    float mn0 = fmaxf(m_i[0][r], mx0[r]);
                    float a0  = exp2f(m_i[0][r] - mn0);
                    m_i[0][r] = mn0; lsum0[r] *= a0;
                    float mn1 = fmaxf(m_i[1][r], mx1[r]);
                    float a1  = exp2f(m_i[1][r] - mn1);
                    m_i[1][r] = mn1; lsum1[r] *= a1;
#pragma unroll
                    for (int dt = 0; dt < 8; ++dt) {
                        o0[dt][r] *= a0;
                        o1[dt][r] *= a1;
                    }
                }
            }
            // P = exp2(S - m) -> LDS (wave-private; same-wave DS ordering)
#pragma unroll
            for (int ct = 0; ct < 4; ++ct)
#pragma unroll
                for (int r = 0; r < 4; ++r) {
                    Ps[w][quad * 4 + r][ct * 16 + col]      = f2bf(exp2f(s0[ct][r] - m_i[0][r]));
                    Ps[w][16 + quad * 4 + r][ct * 16 + col] = f2bf(exp2f(s1[ct][r] - m_i[1][r]));
                }

            // O += P V ; lsum += P * ones. Each vf read feeds BOTH halves.
#pragma unroll
            for (int kt = 0; kt < 2; ++kt) {
                short8 pf0 = *(const short8*)&Ps[w][col][kt * 32 + quad * 8];
                short8 pf1 = *(const short8*)&Ps[w][16 + col][kt * 32 + quad * 8];
#pragma unroll
                for (int dt = 0; dt < 8; ++dt) {
                    short8 vf = *(const short8*)&Vt[dt * 16 + col][kt * 32 + quad * 8];
                    o0[dt] = __builtin_amdgcn_mfma_f32_16x16x32_bf16(pf0, vf, o0[dt], 0, 0, 0);
                    o1[dt] = __builtin_amdgcn_mfma_f32_16x16x32_bf16(pf1, vf, o1[dt], 0, 0, 0);
                }
                lsum0 = __builtin_amdgcn_mfma_f32_16x16x32_bf16(pf0, vone, lsum0, 0, 0, 0);
                lsum1 = __builtin_amdgcn_mfma_f32_16x16x32_bf16(pf1, vone, lsum1, 0, 0, 0);
            }
        }

        __syncthreads();                 // all waves done reading Ks/Vt
        if (pre) {
#pragma unroll
            for (int i = 0; i < 4; ++i) {
                *(float4*)&Ks[jr][kd + i * 8] = pk[i];
                *(float4*)&Vt[vd][vj + i * 8] = pv[i];
            }
            __syncthreads();             // next tile ready
        }
    }

    // epilogue: normalize + store bf16 (lsum row mapping == o row mapping)
#pragma unroll
    for (int r = 0; r < 4; ++r) {
        float inv0 = 1.0f / fmaxf(lsum0[r], 1e-30f);
        float inv1 = 1.0f / fmaxf(lsum1[r], 1e-30f);
        ushort_t* op0 = obuf + (size_t)(bS + wr + quad * 4 + r) * HID_ + h * HD_;
        ushort_t* op1 = obuf + (size_t)(bS + wr + 16 + quad * 4 + r) * HID_ + h * HD_;
#pragma unroll
        for (int dt = 0; dt < 8; ++dt) {
            op0[dt * 16 + col] = f2bf_s(o0[dt][r] * inv0);
            op1[dt * 16 + col] = f2bf_s(o1[dt][r] * inv1);
        }
    }
}

// ---------------------------------------------------------------------------
// fp32 in, fp32 out, bf16 internal.
//   d_out low  [0, 33.5MB):   Q bf16; finally fp32 result rows 0..4095
//   d_out high [33.5, 67MB):  Xb bf16 (prepass) -> O bf16 (flash) -> fp32 result
//   ws: [0, 8.4)   K bf16 rows
//       [8.4,16.8) V bf16 transposed
//       [16.8,29.4) WqkvT bf16 [3072][2048]
//       [33.5,41.9) WoT bf16 [2048][2048]
//       [41.9,43.0) RoPE cos/sin tables fp32 [2048][64] x2
//       after flash: O copied to [0,33.5)  -> ws high-water = 43.0 MB
// ---------------------------------------------------------------------------
extern "C" void kernel_launch(void* const* d_in, const int* in_sizes, int n_in,
                              void* d_out, int out_size, void* d_ws, size_t ws_size,
                              hipStream_t stream) {
    const float* X    = (const float*)d_in[0];   // [8192, 2048] fp32
    const float* Wqkv = (const float*)d_in[1];   // [2048, 3072] fp32
    const float* Wo   = (const float*)d_in[2];   // [2048, 2048] fp32

    ushort_t* qb  = (ushort_t*)d_out;                        // Q bf16
    ushort_t* xh  = (ushort_t*)d_out + (size_t)NTOK * HID_;  // Xb, then O bf16
    ushort_t* kb  = (ushort_t*)d_ws;                         // K rows
    ushort_t* vtg = kb + (size_t)NTOK * KO_N;                // V transposed
    ushort_t* wqt = vtg + (size_t)NTOK * KO_N;               // WqkvT [3072][2048]
    ushort_t* wot = (ushort_t*)d_ws + (size_t)NTOK * HID_;   // WoT   [2048][2048]
    float*    ctab = (float*)(wot + (size_t)HID_ * HID_);    // cos [2048][64]
    float*    stab = ctab + (size_t)S_ * 64;                 // sin [2048][64]
    ushort_t* oa  = (ushort_t*)d_ws;                         // O (after copy)

    // 0) prepasses: X -> bf16 (d_out high); weights -> transposed bf16 (ws);
    //    RoPE tables
    convx_kernel<<<NTOK * HID_ / (256 * 8), 256, 0, stream>>>(X, xh);
    wtrans_kernel<<<dim3(QKV_N / 32, HID_ / 32), 256, 0, stream>>>(Wqkv, wqt, HID_, QKV_N);
    wtrans_kernel<<<dim3(HID_ / 32, HID_ / 32), 256, 0, stream>>>(Wo, wot, HID_, HID_);
    ropetab_kernel<<<(S_ * 64) / 256, 256, 0, stream>>>(ctab, stab);
    // 1) QKV projection: Q -> d_out low, K rows -> ws, V transposed -> ws
    gemm_bt<1><<<dim3(QKV_N / 128, NTOK / 128), 256, 0, stream>>>(
        xh, wqt, qb, kb, vtg, NTOK, QKV_N, HID_);
    // 2) RoPE on Q and K (Q pre-scaled into base-2 softmax domain)
    rope_kernel<<<(NTOK * 20 * 8) / 256, 256, 0, stream>>>(qb, kb, ctab, stab);
    // 3) causal GQA flash attention: O bf16 -> d_out high (Xb dead)
    flash_kernel<<<dim3(S_ / 128, NH_, B_), 256, 0, stream>>>(qb, kb, vtg, xh);
    // 4) move O into ws (K/V/WqkvT dead) so GEMM2 can write all of d_out
    hipMemcpyAsync(oa, xh, (size_t)NTOK * HID_ * sizeof(ushort_t),
                   hipMemcpyDeviceToDevice, stream);
    // 5) output projection: bf16 A, bf16 WoT, fp32 C -> d_out
    gemm_bt<0><<<dim3(HID_ / 128, NTOK / 128), 256, 0, stream>>>(
        oa, wot, d_out, nullptr, nullptr, NTOK, HID_, HID_);
}

// Round 7
// 624.938 us; speedup vs baseline: 1.3150x; 1.3150x over previous
//
#include <hip/hip_runtime.h>

#define B_ 4
#define S_ 2048
#define HID_ 2048
#define NH_ 16
#define NKV_ 4
#define HD_ 128
#define NTOK (B_ * S_)                 // 8192
#define QKV_N 3072                     // (NH + 2*NKV) * HD
#define KO_N 512                       // K-only row length (4 kv heads * 128)
#define SCALE_ 0.08838834764831845f    // 128^-0.5
#define QSC_ 0.12751743f               // SCALE_ * log2(e)  (base-2 softmax)
#define LOG2_10K 13.287712379549449f   // log2(10000)
#define NEG_ -30000.0f

typedef __attribute__((ext_vector_type(8))) short short8;
typedef __attribute__((ext_vector_type(4))) short short4v;
typedef __attribute__((ext_vector_type(4))) float f32x4;
typedef unsigned short ushort_t;
typedef unsigned int uint32;

__device__ __forceinline__ float sanit(float x) {
    if (!(x == x)) x = 0.0f;
    return fminf(fmaxf(x, -65504.0f), 65504.0f);
}
__device__ __forceinline__ ushort_t f2bf(float f) {
    union { float f; uint32 u; } c; c.f = f;
    uint32 u = c.u;
    u += 0x7fffu + ((u >> 16) & 1u);          // round-to-nearest-even
    return (ushort_t)(u >> 16);
}
__device__ __forceinline__ ushort_t f2bf_s(float f) { return f2bf(sanit(f)); }
__device__ __forceinline__ float bf2f(ushort_t h) {
    union { float f; uint32 u; } c; c.u = ((uint32)h) << 16;
    return c.f;
}

// async global->LDS, 16B per lane, linear dest (wave-uniform base + lane*16)
__device__ __forceinline__ void gl16(const ushort_t* g, ushort_t* l) {
    __builtin_amdgcn_global_load_lds(
        (__attribute__((address_space(1))) void*)g,
        (__attribute__((address_space(3))) void*)l, 16, 0, 0);
}

// ---------------------------------------------------------------------------
// Prepass 1: X fp32 [8192][2048] -> bf16 (vectorized, 8 elems/thread)
// ---------------------------------------------------------------------------
__global__ void convx_kernel(const float* __restrict__ X, ushort_t* __restrict__ Xb) {
    size_t i = (size_t)blockIdx.x * blockDim.x + threadIdx.x;
    const float4 a = *(const float4*)(X + i * 8);
    const float4 b = *(const float4*)(X + i * 8 + 4);
    short8 p;
    p[0] = (short)f2bf(a.x); p[1] = (short)f2bf(a.y);
    p[2] = (short)f2bf(a.z); p[3] = (short)f2bf(a.w);
    p[4] = (short)f2bf(b.x); p[5] = (short)f2bf(b.y);
    p[6] = (short)f2bf(b.z); p[7] = (short)f2bf(b.w);
    *(short8*)(Xb + i * 8) = p;
}

// ---------------------------------------------------------------------------
// Prepass 2: W fp32 [K][N] -> Wt bf16 [N][K] (32x32 LDS tile transpose)
// ---------------------------------------------------------------------------
__global__ void wtrans_kernel(const float* __restrict__ W, ushort_t* __restrict__ Wt,
                              int K, int N) {
    __shared__ float tile[32][33];
    const int n0 = blockIdx.x * 32;
    const int k0 = blockIdx.y * 32;
    const int t  = threadIdx.x;        // 256
    const int r  = t >> 3;             // 0..31
    const int c  = (t & 7) * 4;        // 0..28
    const float4 v = *(const float4*)(W + (size_t)(k0 + r) * N + n0 + c);
    tile[r][c] = v.x; tile[r][c + 1] = v.y; tile[r][c + 2] = v.z; tile[r][c + 3] = v.w;
    __syncthreads();
    short4v p;
    p[0] = (short)f2bf(tile[c][r]);
    p[1] = (short)f2bf(tile[c + 1][r]);
    p[2] = (short)f2bf(tile[c + 2][r]);
    p[3] = (short)f2bf(tile[c + 3][r]);
    *(short4v*)(Wt + (size_t)(n0 + r) * K + k0 + c) = p;
}

// ---------------------------------------------------------------------------
// Prepass 3: RoPE cos/sin tables [S][64] fp32
// ---------------------------------------------------------------------------
__global__ void ropetab_kernel(float* __restrict__ ct, float* __restrict__ st) {
    int p = blockIdx.x * blockDim.x + threadIdx.x;   // 0 .. S_*64-1
    int s = p >> 6, d = p & 63;
    float inv = exp2f(-(float)d * (LOG2_10K / 64.0f));
    float ang = (float)s * inv;
    float sn, cs;
    sincosf(ang, &sn, &cs);
    ct[p] = cs; st[p] = sn;
}

// ---------------------------------------------------------------------------
// GEMM: C = A[M,K] @ B, with B given transposed as Bt[N,K]. All bf16 in,
// fp32 acc. m97 structure: 128x128 tile, 4 waves of 64x64, BK=64
// (halves barrier-drain count vs BK=32), global_load_lds staging.
// SPLIT=1 (QKV): cols <2048 -> Q bf16 (C0); 2048..2559 -> K bf16 (C1);
//                2560..3071 -> V TRANSPOSED bf16 (C2)[vcol*8192 + token].
// SPLIT=0: fp32 epilogue into C0 (ld N).
// ---------------------------------------------------------------------------
template <int SPLIT>
__global__ __launch_bounds__(256, 2) void gemm_bt(
    const ushort_t* __restrict__ A, const ushort_t* __restrict__ Bt,
    void* __restrict__ C0, ushort_t* __restrict__ C1, ushort_t* __restrict__ C2,
    int M, int N, int K) {
    __shared__ __align__(16) ushort_t As[128 * 64];   // 16 KB
    __shared__ __align__(16) ushort_t Bs[128 * 64];   // 16 KB

    const int tid  = threadIdx.x;
    const int lane = tid & 63;
    const int w    = tid >> 6;
    const int wm   = (w >> 1) * 64;
    const int wn   = (w & 1) * 64;
    const int m0   = blockIdx.y * 128;
    const int n0   = blockIdx.x * 128;
    const int col  = lane & 15;
    const int quad = lane >> 4;

    f32x4 acc[4][4] = {};

    // staging map: chunk c = i*256 + tid (i=0..3); row = c>>3 (0..127),
    // kc = (c&7)*8; LDS elem = c*8 (linear, matches lane order per wave)
    const ushort_t* agp[4];
    const ushort_t* bgp[4];
    ushort_t* lap[4];
    ushort_t* lbp[4];
#pragma unroll
    for (int i = 0; i < 4; ++i) {
        int c  = i * 256 + tid;
        int rw = c >> 3;
        int kc = (c & 7) * 8;
        agp[i] = A  + (size_t)(m0 + rw) * K + kc;
        bgp[i] = Bt + (size_t)(n0 + rw) * K + kc;
        lap[i] = &As[c * 8];
        lbp[i] = &Bs[c * 8];
    }

    for (int k0 = 0; k0 < K; k0 += 64) {
        __syncthreads();
#pragma unroll
        for (int i = 0; i < 4; ++i) gl16(agp[i] + k0, lap[i]);
#pragma unroll
        for (int i = 0; i < 4; ++i) gl16(bgp[i] + k0, lbp[i]);
        __syncthreads();   // compiler drains vmcnt(0) before s_barrier

#pragma unroll
        for (int kk = 0; kk < 2; ++kk) {
            short8 af[4], bfr[4];
#pragma unroll
            for (int mt = 0; mt < 4; ++mt)
                af[mt] = *(const short8*)&As[(wm + mt * 16 + col) * 64 + kk * 32 + quad * 8];
#pragma unroll
            for (int nt = 0; nt < 4; ++nt)
                bfr[nt] = *(const short8*)&Bs[(wn + nt * 16 + col) * 64 + kk * 32 + quad * 8];
#pragma unroll
            for (int mt = 0; mt < 4; ++mt)
#pragma unroll
                for (int nt = 0; nt < 4; ++nt)
                    acc[mt][nt] = __builtin_amdgcn_mfma_f32_16x16x32_bf16(
                        af[mt], bfr[nt], acc[mt][nt], 0, 0, 0);
        }
    }

    if (SPLIT) {
        if (n0 >= 2560) {
            // V -> transposed global: 4 consecutive tokens packed per store
#pragma unroll
            for (int mt = 0; mt < 4; ++mt)
#pragma unroll
                for (int nt = 0; nt < 4; ++nt) {
                    int cc   = n0 + wn + nt * 16 + col - 2560;  // 0..511
                    int row0 = m0 + wm + mt * 16 + quad * 4;
                    short4v p;
#pragma unroll
                    for (int r = 0; r < 4; ++r) p[r] = (short)f2bf_s(acc[mt][nt][r]);
                    *(short4v*)&C2[(size_t)cc * NTOK + row0] = p;
                }
        } else {
            ushort_t* dst;
            int ldc, coff;
            if (n0 >= 2048) { dst = C1; ldc = KO_N; coff = 2048; }
            else            { dst = (ushort_t*)C0; ldc = HID_; coff = 0; }
#pragma unroll
            for (int mt = 0; mt < 4; ++mt)
#pragma unroll
                for (int nt = 0; nt < 4; ++nt)
#pragma unroll
                    for (int r = 0; r < 4; ++r) {
                        int row = m0 + wm + mt * 16 + quad * 4 + r;
                        int cc  = n0 + wn + nt * 16 + col - coff;
                        dst[(size_t)row * ldc + cc] = f2bf_s(acc[mt][nt][r]);
                    }
        }
    } else {
        float* dst = (float*)C0;
#pragma unroll
        for (int mt = 0; mt < 4; ++mt)
#pragma unroll
            for (int nt = 0; nt < 4; ++nt)
#pragma unroll
                for (int r = 0; r < 4; ++r) {
                    int row = m0 + wm + mt * 16 + quad * 4 + r;
                    int cc  = n0 + wn + nt * 16 + col;
                    dst[(size_t)row * N + cc] = sanit(acc[mt][nt][r]);
                }
    }
}

// ---------------------------------------------------------------------------
// RoPE in-place, table-driven, vectorized (short8). Q pre-scaled by QSC_
// (base-2 softmax domain). One thread per (tok, head, d-octet).
// ---------------------------------------------------------------------------
__global__ void rope_kernel(ushort_t* __restrict__ qbuf, ushort_t* __restrict__ kb,
                            const float* __restrict__ ct, const float* __restrict__ st) {
    int p = blockIdx.x * blockDim.x + threadIdx.x;   // NTOK*20*8
    int d0   = (p & 7) * 8;
    int rest = p >> 3;
    int head = rest % 20;            // 0..15 Q, 16..19 K
    int tok  = rest / 20;
    int s    = tok & (S_ - 1);

    ushort_t* base;
    float sc;
    if (head < 16) { base = qbuf + (size_t)tok * HID_ + head * HD_ + d0; sc = QSC_; }
    else           { base = kb   + (size_t)tok * KO_N + (head - 16) * HD_ + d0; sc = 1.0f; }

    short8 x1v = *(const short8*)base;
    short8 x2v = *(const short8*)(base + 64);
    const float* cp = ct + s * 64 + d0;
    const float* sp = st + s * 64 + d0;
    short8 r1, r2;
#pragma unroll
    for (int e = 0; e < 8; ++e) {
        float x1 = bf2f((ushort_t)x1v[e]);
        float x2 = bf2f((ushort_t)x2v[e]);
        float cs = cp[e], sn = sp[e];
        r1[e] = (short)f2bf_s((x1 * cs - x2 * sn) * sc);
        r2[e] = (short)f2bf_s((x2 * cs + x1 * sn) * sc);
    }
    *(short8*)base        = r1;
    *(short8*)(base + 64) = r2;
}

// ---------------------------------------------------------------------------
// Flash attention, causal, GQA. 8 waves, BQ=128 (16 Q rows/wave), BK=64.
// Q pre-scaled (base-2 domain): interior tiles need NO elementwise fixup.
// Row-sum l computed by MFMA (P x ones) into lsum, rescaled with o under
// defer-max -> no shuffle-sum chain. Register prefetch of next K/V tile.
// (round-4 version, measured 264 us / VGPR 64)
// ---------------------------------------------------------------------------
__global__ __launch_bounds__(512, 4) void flash_kernel(
    const ushort_t* __restrict__ qbuf, const ushort_t* __restrict__ kb,
    const ushort_t* __restrict__ vtg, ushort_t* __restrict__ obuf) {
    __shared__ __align__(16) ushort_t Ks[64][136];   // [j][d], +8 pad
    __shared__ __align__(16) ushort_t Vt[128][72];   // [d][j], +8 pad
    __shared__ __align__(16) ushort_t Ps[8][16][72];

    const int tid  = threadIdx.x;
    const int lane = tid & 63;
    const int w    = tid >> 6;                       // 0..7
    const int col  = lane & 15;
    const int quad = lane >> 4;
    const int q0   = (S_ / 128 - 1 - blockIdx.x) * 128;  // heavy blocks first
    const int h    = blockIdx.y;
    const int b    = blockIdx.z;
    const int kvh  = h >> 2;
    const int bS   = b * S_;

    const int wr    = q0 + w * 16;          // wave's first Q row
    const int wmax  = wr + 15;              // wave's last Q row
    const int i_row = wr + quad * 4;        // + r

    short8 qf[4];
    {
        const ushort_t* qp = qbuf + (size_t)(bS + wr + col) * HID_
                             + h * HD_ + quad * 8;
#pragma unroll
        for (int kt = 0; kt < 4; ++kt) qf[kt] = *(const short8*)(qp + kt * 32);
    }

    short8 vone;
#pragma unroll
    for (int e = 0; e < 8; ++e) vone[e] = (short)0x3F80;   // bf16 1.0

    float m_i[4];
#pragma unroll
    for (int r = 0; r < 4; ++r) m_i[r] = NEG_;
    f32x4 o[8] = {};
    f32x4 lsum = {};

    const int ntiles = q0 / 64 + 2;

    // staging maps (512 threads): K 64x128, V 128x64, 2 float4/thread each
    const int jr = tid >> 3;            // 0..63
    const int kd = (tid & 7) * 16;      // 0..112
    const int vd = tid >> 2;            // 0..127
    const int vj = (tid & 3) * 16;      // 0..48

    const ushort_t* kgb = kb + (size_t)(bS + jr) * KO_N + kvh * HD_ + kd;
    const ushort_t* vgb = vtg + (size_t)(kvh * HD_ + vd) * NTOK + bS + vj;

    float4 pk0, pk1, pv0, pv1;
    // prologue: stage tile 0
    pk0 = *(const float4*)(kgb);
    pk1 = *(const float4*)(kgb + 8);
    pv0 = *(const float4*)(vgb);
    pv1 = *(const float4*)(vgb + 8);
    *(float4*)&Ks[jr][kd]     = pk0;
    *(float4*)&Ks[jr][kd + 8] = pk1;
    *(float4*)&Vt[vd][vj]     = pv0;
    *(float4*)&Vt[vd][vj + 8] = pv1;
    __syncthreads();

    for (int t = 0; t < ntiles; ++t) {
        const int j0 = t * 64;
        const bool pre = (t + 1 < ntiles);
        if (pre) {  // issue next tile's loads now; latency hides under compute
            const ushort_t* kgn = kgb + (size_t)(j0 + 64) * KO_N;
            const ushort_t* vgn = vgb + (j0 + 64);
            pk0 = *(const float4*)(kgn);
            pk1 = *(const float4*)(kgn + 8);
            pv0 = *(const float4*)(vgn);
            pv1 = *(const float4*)(vgn + 8);
        }

        if (j0 <= wmax) {   // wave-uniform: skip fully-masked tiles
            // S = Q K^T  (already scaled: Q carries SCALE_*log2e)
            f32x4 s[4] = {};
#pragma unroll
            for (int ct = 0; ct < 4; ++ct)
#pragma unroll
                for (int kt = 0; kt < 4; ++kt) {
                    short8 kf = *(const short8*)&Ks[ct * 16 + col][kt * 32 + quad * 8];
                    s[ct] = __builtin_amdgcn_mfma_f32_16x16x32_bf16(qf[kt], kf, s[ct], 0, 0, 0);
                }

            // causal mask only on diagonal-adjacent tiles
            if (j0 + 64 > wr) {
#pragma unroll
                for (int ct = 0; ct < 4; ++ct) {
                    int jg = j0 + ct * 16 + col;
#pragma unroll
                    for (int r = 0; r < 4; ++r)
                        if (jg > i_row + r) s[ct][r] = NEG_;
                }
            }

            // row max (row lives in one quad's 16 lanes)
            float mx[4];
#pragma unroll
            for (int r = 0; r < 4; ++r) {
                float m = fmaxf(fmaxf(s[0][r], s[1][r]), fmaxf(s[2][r], s[3][r]));
#pragma unroll
                for (int off = 1; off < 16; off <<= 1)
                    m = fmaxf(m, __shfl_xor(m, off, 64));
                mx[r] = m;
            }
            // defer-max: skip rescale when max growth <= 8 (base-2: P <= 256)
            int ok = 1;
#pragma unroll
            for (int r = 0; r < 4; ++r) ok &= (mx[r] <= m_i[r] + 8.0f) ? 1 : 0;
            if (!__all(ok)) {
#pragma unroll
                for (int r = 0; r < 4; ++r) {
                    float mn = fmaxf(m_i[r], mx[r]);
                    float a  = exp2f(m_i[r] - mn);
                    m_i[r] = mn;
                    lsum[r] *= a;
#pragma unroll
                    for (int dt = 0; dt < 8; ++dt) o[dt][r] *= a;
                }
            }
            // P = exp2(S - m), straight to LDS; row-sum comes via MFMA below
#pragma unroll
            for (int ct = 0; ct < 4; ++ct)
#pragma unroll
                for (int r = 0; r < 4; ++r)
                    Ps[w][quad * 4 + r][ct * 16 + col] = f2bf(exp2f(s[ct][r] - m_i[r]));

            // O += P V ; lsum += P * ones  (wave-private Ps, same-wave ordering)
#pragma unroll
            for (int kt = 0; kt < 2; ++kt) {
                short8 pf = *(const short8*)&Ps[w][col][kt * 32 + quad * 8];
#pragma unroll
                for (int dt = 0; dt < 8; ++dt) {
                    short8 vf = *(const short8*)&Vt[dt * 16 + col][kt * 32 + quad * 8];
                    o[dt] = __builtin_amdgcn_mfma_f32_16x16x32_bf16(pf, vf, o[dt], 0, 0, 0);
                }
                lsum = __builtin_amdgcn_mfma_f32_16x16x32_bf16(pf, vone, lsum, 0, 0, 0);
            }
        }

        __syncthreads();                 // all waves done reading Ks/Vt
        if (pre) {
            *(float4*)&Ks[jr][kd]     = pk0;
            *(float4*)&Ks[jr][kd + 8] = pk1;
            *(float4*)&Vt[vd][vj]     = pv0;
            *(float4*)&Vt[vd][vj + 8] = pv1;
            __syncthreads();             // next tile ready
        }
    }

    // epilogue: normalize + store bf16 (lsum row mapping == o row mapping)
#pragma unroll
    for (int r = 0; r < 4; ++r) {
        float inv = 1.0f / fmaxf(lsum[r], 1e-30f);
        ushort_t* op = obuf + (size_t)(bS + i_row + r) * HID_ + h * HD_;
#pragma unroll
        for (int dt = 0; dt < 8; ++dt)
            op[dt * 16 + col] = f2bf_s(o[dt][r] * inv);
    }
}

// ---------------------------------------------------------------------------
// fp32 in, fp32 out, bf16 internal.
//   d_out low  [0, 33.5MB):   Q bf16; finally fp32 result rows 0..4095
//   d_out high [33.5, 67MB):  Xb bf16 (prepass) -> O bf16 (flash) -> fp32 result
//   ws: [0, 8.4)   K bf16 rows
//       [8.4,16.8) V bf16 transposed
//       [16.8,29.4) WqkvT bf16 [3072][2048]
//       [33.5,41.9) WoT bf16 [2048][2048]
//       [41.9,43.0) RoPE cos/sin tables fp32 [2048][64] x2
//       after flash: O copied to [0,33.5)  -> ws high-water = 43.0 MB
// ---------------------------------------------------------------------------
extern "C" void kernel_launch(void* const* d_in, const int* in_sizes, int n_in,
                              void* d_out, int out_size, void* d_ws, size_t ws_size,
                              hipStream_t stream) {
    const float* X    = (const float*)d_in[0];   // [8192, 2048] fp32
    const float* Wqkv = (const float*)d_in[1];   // [2048, 3072] fp32
    const float* Wo   = (const float*)d_in[2];   // [2048, 2048] fp32

    ushort_t* qb  = (ushort_t*)d_out;                        // Q bf16
    ushort_t* xh  = (ushort_t*)d_out + (size_t)NTOK * HID_;  // Xb, then O bf16
    ushort_t* kb  = (ushort_t*)d_ws;                         // K rows
    ushort_t* vtg = kb + (size_t)NTOK * KO_N;                // V transposed
    ushort_t* wqt = vtg + (size_t)NTOK * KO_N;               // WqkvT [3072][2048]
    ushort_t* wot = (ushort_t*)d_ws + (size_t)NTOK * HID_;   // WoT   [2048][2048]
    float*    ctab = (float*)(wot + (size_t)HID_ * HID_);    // cos [2048][64]
    float*    stab = ctab + (size_t)S_ * 64;                 // sin [2048][64]
    ushort_t* oa  = (ushort_t*)d_ws;                         // O (after copy)

    // 0) prepasses: X -> bf16 (d_out high); weights -> transposed bf16 (ws);
    //    RoPE tables
    convx_kernel<<<NTOK * HID_ / (256 * 8), 256, 0, stream>>>(X, xh);
    wtrans_kernel<<<dim3(QKV_N / 32, HID_ / 32), 256, 0, stream>>>(Wqkv, wqt, HID_, QKV_N);
    wtrans_kernel<<<dim3(HID_ / 32, HID_ / 32), 256, 0, stream>>>(Wo, wot, HID_, HID_);
    ropetab_kernel<<<(S_ * 64) / 256, 256, 0, stream>>>(ctab, stab);
    // 1) QKV projection: Q -> d_out low, K rows -> ws, V transposed -> ws
    gemm_bt<1><<<dim3(QKV_N / 128, NTOK / 128), 256, 0, stream>>>(
        xh, wqt, qb, kb, vtg, NTOK, QKV_N, HID_);
    // 2) RoPE on Q and K (Q pre-scaled into base-2 softmax domain)
    rope_kernel<<<(NTOK * 20 * 8) / 256, 256, 0, stream>>>(qb, kb, ctab, stab);
    // 3) causal GQA flash attention: O bf16 -> d_out high (Xb dead)
    flash_kernel<<<dim3(S_ / 128, NH_, B_), 512, 0, stream>>>(qb, kb, vtg, xh);
    // 4) move O into ws (K/V/WqkvT dead) so GEMM2 can write all of d_out
    hipMemcpyAsync(oa, xh, (size_t)NTOK * HID_ * sizeof(ushort_t),
                   hipMemcpyDeviceToDevice, stream);
    // 5) output projection: bf16 A, bf16 WoT, fp32 C -> d_out
    gemm_bt<0><<<dim3(HID_ / 128, NTOK / 128), 256, 0, stream>>>(
        oa, wot, d_out, nullptr, nullptr, NTOK, HID_, HID_);
}

// Round 8
// 582.847 us; speedup vs baseline: 1.4100x; 1.0722x over previous
//
#include <hip/hip_runtime.h>

#define B_ 4
#define S_ 2048
#define HID_ 2048
#define NH_ 16
#define NKV_ 4
#define HD_ 128
#define NTOK (B_ * S_)                 // 8192
#define QKV_N 3072                     // (NH + 2*NKV) * HD
#define KO_N 512                       // K-only row length (4 kv heads * 128)
#define SCALE_ 0.08838834764831845f    // 128^-0.5
#define QSC_ 0.12751743f               // SCALE_ * log2(e)  (base-2 softmax)
#define LOG2_10K 13.287712379549449f   // log2(10000)
#define NEG_ -30000.0f

typedef __attribute__((ext_vector_type(8))) short short8;
typedef __attribute__((ext_vector_type(4))) short short4v;
typedef __attribute__((ext_vector_type(4))) float f32x4;
typedef unsigned short ushort_t;
typedef unsigned int uint32;

__device__ __forceinline__ float sanit(float x) {
    if (!(x == x)) x = 0.0f;
    return fminf(fmaxf(x, -65504.0f), 65504.0f);
}
__device__ __forceinline__ ushort_t f2bf(float f) {
    union { float f; uint32 u; } c; c.f = f;
    uint32 u = c.u;
    u += 0x7fffu + ((u >> 16) & 1u);          // round-to-nearest-even
    return (ushort_t)(u >> 16);
}
__device__ __forceinline__ ushort_t f2bf_s(float f) { return f2bf(sanit(f)); }
__device__ __forceinline__ float bf2f(ushort_t h) {
    union { float f; uint32 u; } c; c.u = ((uint32)h) << 16;
    return c.f;
}

// async global->LDS, 16B per lane, linear dest (wave-uniform base + lane*16)
__device__ __forceinline__ void gl16(const ushort_t* g, ushort_t* l) {
    __builtin_amdgcn_global_load_lds(
        (__attribute__((address_space(1))) void*)g,
        (__attribute__((address_space(3))) void*)l, 16, 0, 0);
}

// 16-lane max reduce via DPP (row = 16 contiguous lanes). Replaces 4x
// ds_swizzle shuffle with VALU-rate v_mov_dpp; all lanes get the row max.
__device__ __forceinline__ float dpp_max16(float x) {
    union { float f; int i; } c, t;
    c.f = x;
    t.i = __builtin_amdgcn_update_dpp(0, c.i, 0xB1, 0xf, 0xf, true);   // quad_perm(1,0,3,2)
    c.f = fmaxf(c.f, t.f);
    t.i = __builtin_amdgcn_update_dpp(0, c.i, 0x4E, 0xf, 0xf, true);   // quad_perm(2,3,0,1)
    c.f = fmaxf(c.f, t.f);
    t.i = __builtin_amdgcn_update_dpp(0, c.i, 0x141, 0xf, 0xf, true);  // row_half_mirror
    c.f = fmaxf(c.f, t.f);
    t.i = __builtin_amdgcn_update_dpp(0, c.i, 0x140, 0xf, 0xf, true);  // row_mirror
    c.f = fmaxf(c.f, t.f);
    return c.f;
}

// ---------------------------------------------------------------------------
// Prepass 1: X fp32 [8192][2048] -> bf16 (vectorized, 8 elems/thread)
// ---------------------------------------------------------------------------
__global__ void convx_kernel(const float* __restrict__ X, ushort_t* __restrict__ Xb) {
    size_t i = (size_t)blockIdx.x * blockDim.x + threadIdx.x;
    const float4 a = *(const float4*)(X + i * 8);
    const float4 b = *(const float4*)(X + i * 8 + 4);
    short8 p;
    p[0] = (short)f2bf(a.x); p[1] = (short)f2bf(a.y);
    p[2] = (short)f2bf(a.z); p[3] = (short)f2bf(a.w);
    p[4] = (short)f2bf(b.x); p[5] = (short)f2bf(b.y);
    p[6] = (short)f2bf(b.z); p[7] = (short)f2bf(b.w);
    *(short8*)(Xb + i * 8) = p;
}

// ---------------------------------------------------------------------------
// Prepass 2: W fp32 [K][N] -> Wt bf16 [N][K] (32x32 LDS tile transpose)
// ---------------------------------------------------------------------------
__global__ void wtrans_kernel(const float* __restrict__ W, ushort_t* __restrict__ Wt,
                              int K, int N) {
    __shared__ float tile[32][33];
    const int n0 = blockIdx.x * 32;
    const int k0 = blockIdx.y * 32;
    const int t  = threadIdx.x;        // 256
    const int r  = t >> 3;             // 0..31
    const int c  = (t & 7) * 4;        // 0..28
    const float4 v = *(const float4*)(W + (size_t)(k0 + r) * N + n0 + c);
    tile[r][c] = v.x; tile[r][c + 1] = v.y; tile[r][c + 2] = v.z; tile[r][c + 3] = v.w;
    __syncthreads();
    short4v p;
    p[0] = (short)f2bf(tile[c][r]);
    p[1] = (short)f2bf(tile[c + 1][r]);
    p[2] = (short)f2bf(tile[c + 2][r]);
    p[3] = (short)f2bf(tile[c + 3][r]);
    *(short4v*)(Wt + (size_t)(n0 + r) * K + k0 + c) = p;
}

// ---------------------------------------------------------------------------
// Prepass 3: RoPE cos/sin tables [S][64] fp32
// ---------------------------------------------------------------------------
__global__ void ropetab_kernel(float* __restrict__ ct, float* __restrict__ st) {
    int p = blockIdx.x * blockDim.x + threadIdx.x;   // 0 .. S_*64-1
    int s = p >> 6, d = p & 63;
    float inv = exp2f(-(float)d * (LOG2_10K / 64.0f));
    float ang = (float)s * inv;
    float sn, cs;
    sincosf(ang, &sn, &cs);
    ct[p] = cs; st[p] = sn;
}

// ---------------------------------------------------------------------------
// GEMM: C = A[M,K] @ B, with B given transposed as Bt[N,K]. All bf16 in,
// fp32 acc. 256x128 tile, 8 waves of 64x64 (4M x 2N), BK=64,
// global_load_lds staging (linear LDS, no staging VALU). LDS 48 KB.
// SPLIT=1 (QKV): cols <2048 -> Q bf16 (C0); 2048..2559 -> K bf16 (C1);
//                2560..3071 -> V TRANSPOSED bf16 (C2)[vcol*8192 + token].
// SPLIT=0: fp32 epilogue into C0 (ld N).
// ---------------------------------------------------------------------------
template <int SPLIT>
__global__ __launch_bounds__(512, 2) void gemm_bt(
    const ushort_t* __restrict__ A, const ushort_t* __restrict__ Bt,
    void* __restrict__ C0, ushort_t* __restrict__ C1, ushort_t* __restrict__ C2,
    int M, int N, int K) {
    __shared__ __align__(16) ushort_t As[256 * 64];   // 32 KB
    __shared__ __align__(16) ushort_t Bs[128 * 64];   // 16 KB

    const int tid  = threadIdx.x;          // 0..511
    const int lane = tid & 63;
    const int w    = tid >> 6;             // 0..7
    const int wm   = (w >> 1) * 64;        // 0,64,128,192
    const int wn   = (w & 1) * 64;         // 0,64
    const int m0   = blockIdx.y * 256;
    const int n0   = blockIdx.x * 128;
    const int col  = lane & 15;
    const int quad = lane >> 4;

    f32x4 acc[4][4] = {};

    // staging map: chunk c; row = c>>3, kc = (c&7)*8; LDS elem = c*8
    // (lane-linear per wave -> valid global_load_lds dest)
    const ushort_t* agp[4];
    const ushort_t* bgp[2];
    ushort_t* lap[4];
    ushort_t* lbp[2];
#pragma unroll
    for (int i = 0; i < 4; ++i) {
        int c  = i * 512 + tid;
        int rw = c >> 3;
        int kc = (c & 7) * 8;
        agp[i] = A + (size_t)(m0 + rw) * K + kc;
        lap[i] = &As[c * 8];
    }
#pragma unroll
    for (int i = 0; i < 2; ++i) {
        int c  = i * 512 + tid;
        int rw = c >> 3;
        int kc = (c & 7) * 8;
        bgp[i] = Bt + (size_t)(n0 + rw) * K + kc;
        lbp[i] = &Bs[c * 8];
    }

    for (int k0 = 0; k0 < K; k0 += 64) {
        __syncthreads();
#pragma unroll
        for (int i = 0; i < 4; ++i) gl16(agp[i] + k0, lap[i]);
#pragma unroll
        for (int i = 0; i < 2; ++i) gl16(bgp[i] + k0, lbp[i]);
        __syncthreads();   // compiler drains vmcnt(0) before s_barrier

#pragma unroll
        for (int kk = 0; kk < 2; ++kk) {
            short8 af[4], bfr[4];
#pragma unroll
            for (int mt = 0; mt < 4; ++mt)
                af[mt] = *(const short8*)&As[(wm + mt * 16 + col) * 64 + kk * 32 + quad * 8];
#pragma unroll
            for (int nt = 0; nt < 4; ++nt)
                bfr[nt] = *(const short8*)&Bs[(wn + nt * 16 + col) * 64 + kk * 32 + quad * 8];
#pragma unroll
            for (int mt = 0; mt < 4; ++mt)
#pragma unroll
                for (int nt = 0; nt < 4; ++nt)
                    acc[mt][nt] = __builtin_amdgcn_mfma_f32_16x16x32_bf16(
                        af[mt], bfr[nt], acc[mt][nt], 0, 0, 0);
        }
    }

    if (SPLIT) {
        if (n0 >= 2560) {
            // V -> transposed global: 4 consecutive tokens packed per store
#pragma unroll
            for (int mt = 0; mt < 4; ++mt)
#pragma unroll
                for (int nt = 0; nt < 4; ++nt) {
                    int cc   = n0 + wn + nt * 16 + col - 2560;  // 0..511
                    int row0 = m0 + wm + mt * 16 + quad * 4;
                    short4v p;
#pragma unroll
                    for (int r = 0; r < 4; ++r) p[r] = (short)f2bf_s(acc[mt][nt][r]);
                    *(short4v*)&C2[(size_t)cc * NTOK + row0] = p;
                }
        } else {
            ushort_t* dst;
            int ldc, coff;
            if (n0 >= 2048) { dst = C1; ldc = KO_N; coff = 2048; }
            else            { dst = (ushort_t*)C0; ldc = HID_; coff = 0; }
#pragma unroll
            for (int mt = 0; mt < 4; ++mt)
#pragma unroll
                for (int nt = 0; nt < 4; ++nt)
#pragma unroll
                    for (int r = 0; r < 4; ++r) {
                        int row = m0 + wm + mt * 16 + quad * 4 + r;
                        int cc  = n0 + wn + nt * 16 + col - coff;
                        dst[(size_t)row * ldc + cc] = f2bf_s(acc[mt][nt][r]);
                    }
        }
    } else {
        float* dst = (float*)C0;
#pragma unroll
        for (int mt = 0; mt < 4; ++mt)
#pragma unroll
            for (int nt = 0; nt < 4; ++nt)
#pragma unroll
                for (int r = 0; r < 4; ++r) {
                    int row = m0 + wm + mt * 16 + quad * 4 + r;
                    int cc  = n0 + wn + nt * 16 + col;
                    dst[(size_t)row * N + cc] = sanit(acc[mt][nt][r]);
                }
    }
}

// ---------------------------------------------------------------------------
// RoPE in-place, table-driven, vectorized (short8). Q pre-scaled by QSC_
// (base-2 softmax domain). One thread per (tok, head, d-octet).
// ---------------------------------------------------------------------------
__global__ void rope_kernel(ushort_t* __restrict__ qbuf, ushort_t* __restrict__ kb,
                            const float* __restrict__ ct, const float* __restrict__ st) {
    int p = blockIdx.x * blockDim.x + threadIdx.x;   // NTOK*20*8
    int d0   = (p & 7) * 8;
    int rest = p >> 3;
    int head = rest % 20;            // 0..15 Q, 16..19 K
    int tok  = rest / 20;
    int s    = tok & (S_ - 1);

    ushort_t* base;
    float sc;
    if (head < 16) { base = qbuf + (size_t)tok * HID_ + head * HD_ + d0; sc = QSC_; }
    else           { base = kb   + (size_t)tok * KO_N + (head - 16) * HD_ + d0; sc = 1.0f; }

    short8 x1v = *(const short8*)base;
    short8 x2v = *(const short8*)(base + 64);
    const float* cp = ct + s * 64 + d0;
    const float* sp = st + s * 64 + d0;
    short8 r1, r2;
#pragma unroll
    for (int e = 0; e < 8; ++e) {
        float x1 = bf2f((ushort_t)x1v[e]);
        float x2 = bf2f((ushort_t)x2v[e]);
        float cs = cp[e], sn = sp[e];
        r1[e] = (short)f2bf_s((x1 * cs - x2 * sn) * sc);
        r2[e] = (short)f2bf_s((x2 * cs + x1 * sn) * sc);
    }
    *(short8*)base        = r1;
    *(short8*)(base + 64) = r2;
}

// ---------------------------------------------------------------------------
// Flash attention, causal, GQA. 8 waves, BQ=128 (16 Q rows/wave), BK=64.
// Q pre-scaled (base-2 domain); MFMA row-sum; defer-max; DPP max-reduce;
// register prefetch of next K/V tile. (round-4 structure, 264 us base)
// ---------------------------------------------------------------------------
__global__ __launch_bounds__(512, 4) void flash_kernel(
    const ushort_t* __restrict__ qbuf, const ushort_t* __restrict__ kb,
    const ushort_t* __restrict__ vtg, ushort_t* __restrict__ obuf) {
    __shared__ __align__(16) ushort_t Ks[64][136];   // [j][d], +8 pad
    __shared__ __align__(16) ushort_t Vt[128][72];   // [d][j], +8 pad
    __shared__ __align__(16) ushort_t Ps[8][16][72];

    const int tid  = threadIdx.x;
    const int lane = tid & 63;
    const int w    = tid >> 6;                       // 0..7
    const int col  = lane & 15;
    const int quad = lane >> 4;
    const int q0   = (S_ / 128 - 1 - blockIdx.x) * 128;  // heavy blocks first
    const int h    = blockIdx.y;
    const int b    = blockIdx.z;
    const int kvh  = h >> 2;
    const int bS   = b * S_;

    const int wr    = q0 + w * 16;          // wave's first Q row
    const int wmax  = wr + 15;              // wave's last Q row
    const int i_row = wr + quad * 4;        // + r

    short8 qf[4];
    {
        const ushort_t* qp = qbuf + (size_t)(bS + wr + col) * HID_
                             + h * HD_ + quad * 8;
#pragma unroll
        for (int kt = 0; kt < 4; ++kt) qf[kt] = *(const short8*)(qp + kt * 32);
    }

    short8 vone;
#pragma unroll
    for (int e = 0; e < 8; ++e) vone[e] = (short)0x3F80;   // bf16 1.0

    float m_i[4];
#pragma unroll
    for (int r = 0; r < 4; ++r) m_i[r] = NEG_;
    f32x4 o[8] = {};
    f32x4 lsum = {};

    const int ntiles = q0 / 64 + 2;

    // staging maps (512 threads): K 64x128, V 128x64, 2 float4/thread each
    const int jr = tid >> 3;            // 0..63
    const int kd = (tid & 7) * 16;      // 0..112
    const int vd = tid >> 2;            // 0..127
    const int vj = (tid & 3) * 16;      // 0..48

    const ushort_t* kgb = kb + (size_t)(bS + jr) * KO_N + kvh * HD_ + kd;
    const ushort_t* vgb = vtg + (size_t)(kvh * HD_ + vd) * NTOK + bS + vj;

    float4 pk0, pk1, pv0, pv1;
    // prologue: stage tile 0
    pk0 = *(const float4*)(kgb);
    pk1 = *(const float4*)(kgb + 8);
    pv0 = *(const float4*)(vgb);
    pv1 = *(const float4*)(vgb + 8);
    *(float4*)&Ks[jr][kd]     = pk0;
    *(float4*)&Ks[jr][kd + 8] = pk1;
    *(float4*)&Vt[vd][vj]     = pv0;
    *(float4*)&Vt[vd][vj + 8] = pv1;
    __syncthreads();

    for (int t = 0; t < ntiles; ++t) {
        const int j0 = t * 64;
        const bool pre = (t + 1 < ntiles);
        if (pre) {  // issue next tile's loads now; latency hides under compute
            const ushort_t* kgn = kgb + (size_t)(j0 + 64) * KO_N;
            const ushort_t* vgn = vgb + (j0 + 64);
            pk0 = *(const float4*)(kgn);
            pk1 = *(const float4*)(kgn + 8);
            pv0 = *(const float4*)(vgn);
            pv1 = *(const float4*)(vgn + 8);
        }

        if (j0 <= wmax) {   // wave-uniform: skip fully-masked tiles
            // S = Q K^T  (already scaled: Q carries SCALE_*log2e)
            f32x4 s[4] = {};
#pragma unroll
            for (int ct = 0; ct < 4; ++ct)
#pragma unroll
                for (int kt = 0; kt < 4; ++kt) {
                    short8 kf = *(const short8*)&Ks[ct * 16 + col][kt * 32 + quad * 8];
                    s[ct] = __builtin_amdgcn_mfma_f32_16x16x32_bf16(qf[kt], kf, s[ct], 0, 0, 0);
                }

            // causal mask only on diagonal-adjacent tiles
            if (j0 + 64 > wr) {
#pragma unroll
                for (int ct = 0; ct < 4; ++ct) {
                    int jg = j0 + ct * 16 + col;
#pragma unroll
                    for (int r = 0; r < 4; ++r)
                        if (jg > i_row + r) s[ct][r] = NEG_;
                }
            }

            // row max via DPP (row lives in one quad's contiguous 16 lanes)
            float mx[4];
#pragma unroll
            for (int r = 0; r < 4; ++r)
                mx[r] = dpp_max16(fmaxf(fmaxf(s[0][r], s[1][r]),
                                        fmaxf(s[2][r], s[3][r])));
            // defer-max: skip rescale when max growth <= 8 (base-2: P <= 256)
            int ok = 1;
#pragma unroll
            for (int r = 0; r < 4; ++r) ok &= (mx[r] <= m_i[r] + 8.0f) ? 1 : 0;
            if (!__all(ok)) {
#pragma unroll
                for (int r = 0; r < 4; ++r) {
                    float mn = fmaxf(m_i[r], mx[r]);
                    float a  = exp2f(m_i[r] - mn);
                    m_i[r] = mn;
                    lsum[r] *= a;
#pragma unroll
                    for (int dt = 0; dt < 8; ++dt) o[dt][r] *= a;
                }
            }
            // P = exp2(S - m), straight to LDS; row-sum comes via MFMA below
#pragma unroll
            for (int ct = 0; ct < 4; ++ct)
#pragma unroll
                for (int r = 0; r < 4; ++r)
                    Ps[w][quad * 4 + r][ct * 16 + col] = f2bf(exp2f(s[ct][r] - m_i[r]));

            // O += P V ; lsum += P * ones  (wave-private Ps, same-wave ordering)
#pragma unroll
            for (int kt = 0; kt < 2; ++kt) {
                short8 pf = *(const short8*)&Ps[w][col][kt * 32 + quad * 8];
#pragma unroll
                for (int dt = 0; dt < 8; ++dt) {
                    short8 vf = *(const short8*)&Vt[dt * 16 + col][kt * 32 + quad * 8];
                    o[dt] = __builtin_amdgcn_mfma_f32_16x16x32_bf16(pf, vf, o[dt], 0, 0, 0);
                }
                lsum = __builtin_amdgcn_mfma_f32_16x16x32_bf16(pf, vone, lsum, 0, 0, 0);
            }
        }

        __syncthreads();                 // all waves done reading Ks/Vt
        if (pre) {
            *(float4*)&Ks[jr][kd]     = pk0;
            *(float4*)&Ks[jr][kd + 8] = pk1;
            *(float4*)&Vt[vd][vj]     = pv0;
            *(float4*)&Vt[vd][vj + 8] = pv1;
            __syncthreads();             // next tile ready
        }
    }

    // epilogue: normalize + store bf16 (lsum row mapping == o row mapping)
#pragma unroll
    for (int r = 0; r < 4; ++r) {
        float inv = 1.0f / fmaxf(lsum[r], 1e-30f);
        ushort_t* op = obuf + (size_t)(bS + i_row + r) * HID_ + h * HD_;
#pragma unroll
        for (int dt = 0; dt < 8; ++dt)
            op[dt * 16 + col] = f2bf_s(o[dt][r] * inv);
    }
}

// ---------------------------------------------------------------------------
// fp32 in, fp32 out, bf16 internal.
//   d_out low  [0, 33.5MB):   Q bf16; finally fp32 result rows 0..4095
//   d_out high [33.5, 67MB):  Xb bf16 (prepass) -> fp32 result rows 4096..8191
//   ws: [0, 8.4)    K bf16 rows
//       [8.4,16.8)  V bf16 transposed
//       [16.8,29.4) WqkvT bf16 [3072][2048]
//       [33.5,41.9) WoT bf16 [2048][2048]
//       [41.9,43.0) RoPE cos/sin tables fp32 [2048][64] x2
//       [43.0,76.5) O bf16 (direct flash output, if ws_size allows;
//                   else O goes to d_out high + memcpy to ws[0,33.5))
// ---------------------------------------------------------------------------
extern "C" void kernel_launch(void* const* d_in, const int* in_sizes, int n_in,
                              void* d_out, int out_size, void* d_ws, size_t ws_size,
                              hipStream_t stream) {
    const float* X    = (const float*)d_in[0];   // [8192, 2048] fp32
    const float* Wqkv = (const float*)d_in[1];   // [2048, 3072] fp32
    const float* Wo   = (const float*)d_in[2];   // [2048, 2048] fp32

    ushort_t* qb  = (ushort_t*)d_out;                        // Q bf16
    ushort_t* xh  = (ushort_t*)d_out + (size_t)NTOK * HID_;  // Xb (prepass)
    ushort_t* kb  = (ushort_t*)d_ws;                         // K rows
    ushort_t* vtg = kb + (size_t)NTOK * KO_N;                // V transposed
    ushort_t* wqt = vtg + (size_t)NTOK * KO_N;               // WqkvT [3072][2048]
    ushort_t* wot = (ushort_t*)d_ws + (size_t)NTOK * HID_;   // WoT   [2048][2048]
    float*    ctab = (float*)(wot + (size_t)HID_ * HID_);    // cos [2048][64]
    float*    stab = ctab + (size_t)S_ * 64;                 // sin [2048][64]
    ushort_t* ohi  = (ushort_t*)(stab + (size_t)S_ * 64);    // O direct @43.0MB

    const size_t osize  = (size_t)NTOK * HID_ * sizeof(ushort_t);     // 33.5 MB
    const size_t need   = (size_t)((char*)ohi - (char*)d_ws) + osize; // 76.5 MB
    const bool   direct = (ws_size >= need);

    ushort_t* oflash = direct ? ohi : xh;        // where flash writes O
    ushort_t* oa     = direct ? ohi : (ushort_t*)d_ws;  // where GEMM2 reads O

    // 0) prepasses: X -> bf16 (d_out high); weights -> transposed bf16 (ws);
    //    RoPE tables
    convx_kernel<<<NTOK * HID_ / (256 * 8), 256, 0, stream>>>(X, xh);
    wtrans_kernel<<<dim3(QKV_N / 32, HID_ / 32), 256, 0, stream>>>(Wqkv, wqt, HID_, QKV_N);
    wtrans_kernel<<<dim3(HID_ / 32, HID_ / 32), 256, 0, stream>>>(Wo, wot, HID_, HID_);
    ropetab_kernel<<<(S_ * 64) / 256, 256, 0, stream>>>(ctab, stab);
    // 1) QKV projection: Q -> d_out low, K rows -> ws, V transposed -> ws
    gemm_bt<1><<<dim3(QKV_N / 128, NTOK / 256), 512, 0, stream>>>(
        xh, wqt, qb, kb, vtg, NTOK, QKV_N, HID_);
    // 2) RoPE on Q and K (Q pre-scaled into base-2 softmax domain)
    rope_kernel<<<(NTOK * 20 * 8) / 256, 256, 0, stream>>>(qb, kb, ctab, stab);
    // 3) causal GQA flash attention: O bf16 -> ws high (or d_out high fallback)
    flash_kernel<<<dim3(S_ / 128, NH_, B_), 512, 0, stream>>>(qb, kb, vtg, oflash);
    // 4) fallback only: move O into ws so GEMM2 can write all of d_out
    if (!direct)
        hipMemcpyAsync(oa, oflash, osize, hipMemcpyDeviceToDevice, stream);
    // 5) output projection: bf16 A, bf16 WoT, fp32 C -> d_out
    gemm_bt<0><<<dim3(HID_ / 128, NTOK / 256), 512, 0, stream>>>(
        oa, wot, d_out, nullptr, nullptr, NTOK, HID_, HID_);
}